// Round 1
// baseline (219.436 us; speedup 1.0000x reference)
//
#include <hip/hip_runtime.h>
#include <math.h>

#define S_LEN 1024
#define D_DIM 64
#define NBH   16
#define NH    8

// ---------------- Kernel 1: dp[bh,s,t] = (1/8) * sum_d Q[bh,s,d]*K[bh,t,d] ----
__global__ __launch_bounds__(256) void qk_kernel(const float* __restrict__ q,
                                                 const float* __restrict__ kmat,
                                                 float* __restrict__ dp) {
    __shared__ float Qs[64][65];
    __shared__ float Ks[64][65];
    const int bh = blockIdx.z;
    const int ti = blockIdx.y;
    const int tj = blockIdx.x;
    const int tid = threadIdx.x;
    const float* qb = q    + ((size_t)bh * S_LEN + ti * 64) * D_DIM;
    const float* kb = kmat + ((size_t)bh * S_LEN + tj * 64) * D_DIM;
    #pragma unroll
    for (int p = 0; p < 4; ++p) {
        int idx = p * 256 + tid;          // 0..1023
        int r = idx >> 4;                 // 0..63
        int c = (idx & 15) << 2;          // 0,4,...,60
        float4 qv = *(const float4*)(qb + r * D_DIM + c);
        Qs[r][c+0] = qv.x; Qs[r][c+1] = qv.y; Qs[r][c+2] = qv.z; Qs[r][c+3] = qv.w;
        float4 kv = *(const float4*)(kb + r * D_DIM + c);
        Ks[r][c+0] = kv.x; Ks[r][c+1] = kv.y; Ks[r][c+2] = kv.z; Ks[r][c+3] = kv.w;
    }
    __syncthreads();
    const int tx = tid & 15, ty = tid >> 4;
    float acc[4][4] = {};
    #pragma unroll 4
    for (int k = 0; k < 64; ++k) {
        float ar[4], br[4];
        #pragma unroll
        for (int a = 0; a < 4; ++a) ar[a] = Qs[ty*4+a][k];
        #pragma unroll
        for (int b = 0; b < 4; ++b) br[b] = Ks[tx*4+b][k];
        #pragma unroll
        for (int a = 0; a < 4; ++a)
            #pragma unroll
            for (int b = 0; b < 4; ++b)
                acc[a][b] = fmaf(ar[a], br[b], acc[a][b]);
    }
    float* ob = dp + (size_t)bh * S_LEN * S_LEN;
    #pragma unroll
    for (int a = 0; a < 4; ++a) {
        int row = ti*64 + ty*4 + a;
        int col = tj*64 + tx*4;
        float4 o;
        o.x = acc[a][0]*0.125f; o.y = acc[a][1]*0.125f;
        o.z = acc[a][2]*0.125f; o.w = acc[a][3]*0.125f;
        *(float4*)(ob + (size_t)row * S_LEN + col) = o;
    }
}

// ------------- Kernel 2: fused conv(3x3,4f)+leaky+linear+mask+softmax --------
__global__ __launch_bounds__(256) void conv_softmax_kernel(
    const float* __restrict__ dp, const int* __restrict__ mask,
    const float* __restrict__ conv_w, const float* __restrict__ conv_b,
    const float* __restrict__ lin_w, const float* __restrict__ lin_b,
    float* __restrict__ attn) {
    __shared__ float rows[3][S_LEN];
    __shared__ float red[8];
    const int s  = blockIdx.x;
    const int bh = blockIdx.y;
    const int b  = bh >> 3;               // bh / NH
    const int tid = threadIdx.x;
    const float* base = dp + (size_t)bh * S_LEN * S_LEN;
    #pragma unroll
    for (int r = 0; r < 3; ++r) {
        int sr = s - 1 + r;
        float4* dst = (float4*)rows[r];
        if (sr >= 0 && sr < S_LEN) {
            const float4* src = (const float4*)(base + (size_t)sr * S_LEN);
            dst[tid] = src[tid];          // 256 thr * float4 = 1024 floats
        } else {
            dst[tid] = make_float4(0.f, 0.f, 0.f, 0.f);
        }
    }
    __syncthreads();

    float w[4][9];
    #pragma unroll
    for (int f = 0; f < 4; ++f)
        #pragma unroll
        for (int i = 0; i < 9; ++i) w[f][i] = conv_w[f*9+i];
    float cb[4], lw[4];
    #pragma unroll
    for (int f = 0; f < 4; ++f) { cb[f] = conv_b[f]; lw[f] = lin_w[f]; }
    const float lb = lin_b[0];
    const int* mrow = mask + ((size_t)b * S_LEN + s) * S_LEN;

    float pre[4];
    #pragma unroll
    for (int j = 0; j < 4; ++j) {
        int t = j*256 + tid;
        float v[9];
        #pragma unroll
        for (int di = 0; di < 3; ++di) {
            v[di*3+0] = (t >= 1)        ? rows[di][t-1] : 0.f;
            v[di*3+1] =                   rows[di][t];
            v[di*3+2] = (t < S_LEN-1)   ? rows[di][t+1] : 0.f;
        }
        float p = lb;
        #pragma unroll
        for (int f = 0; f < 4; ++f) {
            float c = cb[f];
            #pragma unroll
            for (int i = 0; i < 9; ++i) c = fmaf(w[f][i], v[i], c);
            float act = c > 0.f ? c : 0.01f * c;
            p = fmaf(lw[f], act, p);
        }
        if (mrow[t] == 0) p = -1e30f;
        pre[j] = p;
    }

    // --- softmax over the 1024 row elements ---
    float m = fmaxf(fmaxf(pre[0], pre[1]), fmaxf(pre[2], pre[3]));
    #pragma unroll
    for (int off = 32; off > 0; off >>= 1) m = fmaxf(m, __shfl_down(m, off));
    const int lane = tid & 63, wid = tid >> 6;
    if (lane == 0) red[wid] = m;
    __syncthreads();
    const float rowmax = fmaxf(fmaxf(red[0], red[1]), fmaxf(red[2], red[3]));

    float e[4], lsum = 0.f;
    #pragma unroll
    for (int j = 0; j < 4; ++j) { e[j] = __expf(pre[j] - rowmax); lsum += e[j]; }
    #pragma unroll
    for (int off = 32; off > 0; off >>= 1) lsum += __shfl_down(lsum, off);
    if (lane == 0) red[4+wid] = lsum;
    __syncthreads();
    const float inv = 1.0f / (red[4] + red[5] + red[6] + red[7]);

    float* arow = attn + ((size_t)bh * S_LEN + s) * S_LEN;
    #pragma unroll
    for (int j = 0; j < 4; ++j) arow[j*256 + tid] = e[j] * inv;
}

// ---------------- Kernel 3: out[bh,s,d] = sum_t attn[bh,s,t]*V[bh,t,d] -------
__global__ __launch_bounds__(256) void av_kernel(const float* __restrict__ attn,
                                                 const float* __restrict__ vmat,
                                                 float* __restrict__ out) {
    __shared__ float As[64][65];
    __shared__ float Vs[64][65];
    const int ti = blockIdx.x;
    const int bh = blockIdx.y;
    const int tid = threadIdx.x;
    const int tx = tid & 15, ty = tid >> 4;
    const float* ab = attn + ((size_t)bh * S_LEN + ti * 64) * S_LEN;
    const float* vb = vmat + (size_t)bh * S_LEN * D_DIM;
    float acc[4][4] = {};
    for (int kk = 0; kk < S_LEN; kk += 64) {
        #pragma unroll
        for (int p = 0; p < 4; ++p) {
            int idx = p*256 + tid;
            int r = idx >> 4;
            int c = (idx & 15) << 2;
            float4 av = *(const float4*)(ab + (size_t)r * S_LEN + kk + c);
            As[r][c+0] = av.x; As[r][c+1] = av.y; As[r][c+2] = av.z; As[r][c+3] = av.w;
            float4 vv = *(const float4*)(vb + (size_t)(kk + r) * D_DIM + c);
            Vs[r][c+0] = vv.x; Vs[r][c+1] = vv.y; Vs[r][c+2] = vv.z; Vs[r][c+3] = vv.w;
        }
        __syncthreads();
        #pragma unroll 4
        for (int k = 0; k < 64; ++k) {
            float ar[4], br[4];
            #pragma unroll
            for (int a = 0; a < 4; ++a) ar[a] = As[ty*4+a][k];
            #pragma unroll
            for (int b = 0; b < 4; ++b) br[b] = Vs[k][tx*4+b];
            #pragma unroll
            for (int a = 0; a < 4; ++a)
                #pragma unroll
                for (int b = 0; b < 4; ++b)
                    acc[a][b] = fmaf(ar[a], br[b], acc[a][b]);
        }
        __syncthreads();
    }
    float* ob = out + ((size_t)bh * S_LEN + ti * 64) * D_DIM;
    #pragma unroll
    for (int a = 0; a < 4; ++a) {
        float4 o;
        o.x = acc[a][0]; o.y = acc[a][1]; o.z = acc[a][2]; o.w = acc[a][3];
        *(float4*)(ob + (size_t)(ty*4+a) * D_DIM + tx*4) = o;
    }
}

extern "C" void kernel_launch(void* const* d_in, const int* in_sizes, int n_in,
                              void* d_out, int out_size, void* d_ws, size_t ws_size,
                              hipStream_t stream) {
    const float* q      = (const float*)d_in[0];
    const float* k      = (const float*)d_in[1];
    const float* v      = (const float*)d_in[2];
    const int*   mask   = (const int*)d_in[3];
    const float* conv_w = (const float*)d_in[4];
    const float* conv_b = (const float*)d_in[5];
    const float* lin_w  = (const float*)d_in[6];
    const float* lin_b  = (const float*)d_in[7];
    float* out = (float*)d_out;

    float* dp   = (float*)d_ws;                            // 16*1024*1024 fp32 = 64 MiB
    float* attn = dp + (size_t)NBH * S_LEN * S_LEN;        // another 64 MiB

    qk_kernel<<<dim3(16, 16, NBH), 256, 0, stream>>>(q, k, dp);
    conv_softmax_kernel<<<dim3(S_LEN, NBH), 256, 0, stream>>>(
        dp, mask, conv_w, conv_b, lin_w, lin_b, attn);
    av_kernel<<<dim3(16, NBH), 256, 0, stream>>>(attn, v, out);
}

// Round 2
// 196.912 us; speedup vs baseline: 1.1144x; 1.1144x over previous
//
#include <hip/hip_runtime.h>
#include <math.h>

#define S_LEN 1024
#define D_DIM 64
#define NBH   16

typedef __attribute__((ext_vector_type(8))) short short8;   // 8 bf16 in 4 VGPRs
typedef __attribute__((ext_vector_type(4))) float f32x4;

// Split fp32 -> (hi, lo) bf16 pair, round-to-nearest-even.
__device__ __forceinline__ void split8(const float* __restrict__ x,
                                       short8& hi, short8& lo) {
    #pragma unroll
    for (int j = 0; j < 8; ++j) {
        float xv = x[j];
        unsigned u = __float_as_uint(xv);
        unsigned h = (u + 0x7FFFu + ((u >> 16) & 1u)) >> 16;
        float hf = __uint_as_float(h << 16);
        float l = xv - hf;
        unsigned ul = __float_as_uint(l);
        unsigned hl = (ul + 0x7FFFu + ((ul >> 16) & 1u)) >> 16;
        hi[j] = (short)h;
        lo[j] = (short)hl;
    }
}

// --------- Kernel 1: dp[bh,s,t] = (1/8) * sum_d Q[bh,s,d]*K[bh,t,d] (MFMA) ---
// grid (64 s-tiles, 16 bh), block 256 = 4 waves; wave w covers t in [w*256, w*256+256)
__global__ __launch_bounds__(256) void qk_mfma(const float* __restrict__ q,
                                               const float* __restrict__ kmat,
                                               float* __restrict__ dp) {
    const int st = blockIdx.x, bh = blockIdx.y;
    const int tid = threadIdx.x;
    const int wave = tid >> 6, lane = tid & 63;
    const int m = lane & 15, quad = lane >> 4;

    // A fragment: Q[s0+m][k], k = chunk*32 + quad*8 + j
    const float* qb = q + ((size_t)bh * S_LEN + st * 16 + m) * D_DIM + quad * 8;
    float a[16];
    *(float4*)(a + 0)  = *(const float4*)(qb + 0);
    *(float4*)(a + 4)  = *(const float4*)(qb + 4);
    *(float4*)(a + 8)  = *(const float4*)(qb + 32);
    *(float4*)(a + 12) = *(const float4*)(qb + 36);
    short8 ahi0, alo0, ahi1, alo1;
    split8(a + 0, ahi0, alo0);
    split8(a + 8, ahi1, alo1);

    const float* kbase = kmat + ((size_t)bh * S_LEN + m) * D_DIM + quad * 8;
    float* dpb = dp + (size_t)bh * S_LEN * S_LEN;

    for (int tt = 0; tt < 16; ++tt) {
        const int t0 = wave * 256 + tt * 16;
        const float* kb = kbase + (size_t)t0 * D_DIM;
        float b[16];
        *(float4*)(b + 0)  = *(const float4*)(kb + 0);
        *(float4*)(b + 4)  = *(const float4*)(kb + 4);
        *(float4*)(b + 8)  = *(const float4*)(kb + 32);
        *(float4*)(b + 12) = *(const float4*)(kb + 36);
        short8 bhi0, blo0, bhi1, blo1;
        split8(b + 0, bhi0, blo0);
        split8(b + 8, bhi1, blo1);

        f32x4 acc = {0.f, 0.f, 0.f, 0.f};
        acc = __builtin_amdgcn_mfma_f32_16x16x32_bf16(ahi0, bhi0, acc, 0, 0, 0);
        acc = __builtin_amdgcn_mfma_f32_16x16x32_bf16(ahi0, blo0, acc, 0, 0, 0);
        acc = __builtin_amdgcn_mfma_f32_16x16x32_bf16(alo0, bhi0, acc, 0, 0, 0);
        acc = __builtin_amdgcn_mfma_f32_16x16x32_bf16(ahi1, bhi1, acc, 0, 0, 0);
        acc = __builtin_amdgcn_mfma_f32_16x16x32_bf16(ahi1, blo1, acc, 0, 0, 0);
        acc = __builtin_amdgcn_mfma_f32_16x16x32_bf16(alo1, bhi1, acc, 0, 0, 0);

        // C/D: col = lane&15 (t), row = quad*4 + r (s)
        #pragma unroll
        for (int r = 0; r < 4; ++r) {
            dpb[(size_t)(st * 16 + quad * 4 + r) * S_LEN + t0 + m] = acc[r] * 0.125f;
        }
    }
}

// ------------- Kernel 2: fused conv(3x3,4f)+leaky+linear+mask+softmax --------
__global__ __launch_bounds__(256) void conv_softmax_kernel(
    const float* __restrict__ dp, const int* __restrict__ mask,
    const float* __restrict__ conv_w, const float* __restrict__ conv_b,
    const float* __restrict__ lin_w, const float* __restrict__ lin_b,
    float* __restrict__ attn) {
    __shared__ float rows[3][S_LEN];
    __shared__ float red[8];
    const int s  = blockIdx.x;
    const int bh = blockIdx.y;
    const int b  = bh >> 3;
    const int tid = threadIdx.x;
    const float* base = dp + (size_t)bh * S_LEN * S_LEN;

    float cen[3][4];
    #pragma unroll
    for (int r = 0; r < 3; ++r) {
        int sr = s - 1 + r;
        float4 val;
        if (sr >= 0 && sr < S_LEN)
            val = *(const float4*)(base + (size_t)sr * S_LEN + tid * 4);
        else
            val = make_float4(0.f, 0.f, 0.f, 0.f);
        cen[r][0] = val.x; cen[r][1] = val.y; cen[r][2] = val.z; cen[r][3] = val.w;
        ((float4*)rows[r])[tid] = val;
    }
    __syncthreads();

    float lft[3], rgt[3];
    #pragma unroll
    for (int r = 0; r < 3; ++r) {
        lft[r] = (tid > 0)   ? rows[r][tid * 4 - 1] : 0.f;
        rgt[r] = (tid < 255) ? rows[r][tid * 4 + 4] : 0.f;
    }

    float w[4][9];
    #pragma unroll
    for (int f = 0; f < 4; ++f)
        #pragma unroll
        for (int i = 0; i < 9; ++i) w[f][i] = conv_w[f * 9 + i];
    float cb[4], lw[4];
    #pragma unroll
    for (int f = 0; f < 4; ++f) { cb[f] = conv_b[f]; lw[f] = lin_w[f]; }
    const float lb = lin_b[0];
    const int* mrow = mask + ((size_t)b * S_LEN + s) * S_LEN;
    const int4 mv = *(const int4*)(mrow + tid * 4);
    const int mk[4] = {mv.x, mv.y, mv.z, mv.w};

    float p[4];
    #pragma unroll
    for (int c = 0; c < 4; ++c) {
        float v[9];
        #pragma unroll
        for (int di = 0; di < 3; ++di) {
            v[di*3+0] = (c == 0) ? lft[di] : cen[di][c-1];
            v[di*3+1] = cen[di][c];
            v[di*3+2] = (c == 3) ? rgt[di] : cen[di][c+1];
        }
        float acc = lb;
        #pragma unroll
        for (int f = 0; f < 4; ++f) {
            float cv = cb[f];
            #pragma unroll
            for (int i = 0; i < 9; ++i) cv = fmaf(w[f][i], v[i], cv);
            float act = cv > 0.f ? cv : 0.01f * cv;
            acc = fmaf(lw[f], act, acc);
        }
        p[c] = (mk[c] == 0) ? -1e30f : acc;
    }

    float mx = fmaxf(fmaxf(p[0], p[1]), fmaxf(p[2], p[3]));
    #pragma unroll
    for (int off = 32; off > 0; off >>= 1) mx = fmaxf(mx, __shfl_down(mx, off));
    const int lane = tid & 63, wid = tid >> 6;
    if (lane == 0) red[wid] = mx;
    __syncthreads();
    const float rowmax = fmaxf(fmaxf(red[0], red[1]), fmaxf(red[2], red[3]));

    float e[4], ls = 0.f;
    #pragma unroll
    for (int c = 0; c < 4; ++c) { e[c] = __expf(p[c] - rowmax); ls += e[c]; }
    #pragma unroll
    for (int off = 32; off > 0; off >>= 1) ls += __shfl_down(ls, off);
    if (lane == 0) red[4 + wid] = ls;
    __syncthreads();
    const float inv = 1.0f / (red[4] + red[5] + red[6] + red[7]);

    float4 o;
    o.x = e[0] * inv; o.y = e[1] * inv; o.z = e[2] * inv; o.w = e[3] * inv;
    *(float4*)(attn + ((size_t)bh * S_LEN + s) * S_LEN + tid * 4) = o;
}

// --------- Kernel 3: out[bh,s,d] = sum_t attn[bh,s,t]*V[bh,t,d] (MFMA) -------
// grid (64 s-tiles, 16 bh), block 256 = 4 waves; wave w handles d-tile d0 = w*16
__global__ __launch_bounds__(256) void av_mfma(const float* __restrict__ attn,
                                               const float* __restrict__ vmat,
                                               float* __restrict__ out) {
    const int st = blockIdx.x, bh = blockIdx.y;
    const int tid = threadIdx.x;
    const int wave = tid >> 6, lane = tid & 63;
    const int m = lane & 15, quad = lane >> 4;
    const int d0 = wave * 16;

    const float* ab = attn + ((size_t)bh * S_LEN + st * 16 + m) * S_LEN;
    const float* vb = vmat + (size_t)bh * S_LEN * D_DIM + d0 + m;

    f32x4 acc = {0.f, 0.f, 0.f, 0.f};
    for (int t0 = 0; t0 < S_LEN; t0 += 32) {
        // A fragment: attn[s0+m][t0 + quad*8 + j]
        float a[8];
        *(float4*)(a + 0) = *(const float4*)(ab + t0 + quad * 8 + 0);
        *(float4*)(a + 4) = *(const float4*)(ab + t0 + quad * 8 + 4);
        // B fragment: V[t0 + quad*8 + j][d0 + m]
        float bfr[8];
        #pragma unroll
        for (int j = 0; j < 8; ++j)
            bfr[j] = vb[(size_t)(t0 + quad * 8 + j) * D_DIM];

        short8 ahi, alo, bhi, blo;
        split8(a, ahi, alo);
        split8(bfr, bhi, blo);
        acc = __builtin_amdgcn_mfma_f32_16x16x32_bf16(ahi, bhi, acc, 0, 0, 0);
        acc = __builtin_amdgcn_mfma_f32_16x16x32_bf16(ahi, blo, acc, 0, 0, 0);
        acc = __builtin_amdgcn_mfma_f32_16x16x32_bf16(alo, bhi, acc, 0, 0, 0);
    }

    // C/D: col = lane&15 (d), row = quad*4 + r (s)
    #pragma unroll
    for (int r = 0; r < 4; ++r) {
        out[(size_t)((size_t)bh * S_LEN + st * 16 + quad * 4 + r) * D_DIM + d0 + m] = acc[r];
    }
}

extern "C" void kernel_launch(void* const* d_in, const int* in_sizes, int n_in,
                              void* d_out, int out_size, void* d_ws, size_t ws_size,
                              hipStream_t stream) {
    const float* q      = (const float*)d_in[0];
    const float* k      = (const float*)d_in[1];
    const float* v      = (const float*)d_in[2];
    const int*   mask   = (const int*)d_in[3];
    const float* conv_w = (const float*)d_in[4];
    const float* conv_b = (const float*)d_in[5];
    const float* lin_w  = (const float*)d_in[6];
    const float* lin_b  = (const float*)d_in[7];
    float* out = (float*)d_out;

    float* dp   = (float*)d_ws;                            // 64 MiB
    float* attn = dp + (size_t)NBH * S_LEN * S_LEN;        // 64 MiB

    qk_mfma<<<dim3(64, NBH), 256, 0, stream>>>(q, k, dp);
    conv_softmax_kernel<<<dim3(S_LEN, NBH), 256, 0, stream>>>(
        dp, mask, conv_w, conv_b, lin_w, lin_b, attn);
    av_mfma<<<dim3(64, NBH), 256, 0, stream>>>(attn, v, out);
}